// Round 5
// baseline (186.558 us; speedup 1.0000x reference)
//
#include <hip/hip_runtime.h>

#define B_  4096
#define G_  31
#define GG_ 961      // G*G
#define P_  8
#define C_  36       // P*(P+1)/2
#define R_  2        // b-values per block (kept tiny: register-pressure-first)

// One launch. Block = 256 threads = 4 waves; block owns R_=2 consecutive b's
// and sweeps all 961 gh cells in 4 passes of 256 (param read once, coalesced:
// 64 lanes x 32B = 2KB contiguous per wave per b).
//
// Register-pressure-first: round 3 proved the AMDGPU allocator squeezes to
// 64 VGPRs and spills wholesale (284 MB scratch writeback) when live state
// exceeds it, regardless of __launch_bounds__ caps. Worst-case live set here
// (pv 16 + all 9 coeff quads hoisted 36 + acc/s 4 + addr ~8) ~= 64 -> no
// spill is possible even at the allocator's favorite budget.
// Coeff cost of R=2: ~295 MB of L2-resident reads (~8.5 us at L2 BW),
// hidden under the 126 MB / ~20 us HBM param stream.
// Reduction: 64-lane butterfly -> 16B LDS -> exclusive store (no atomics).
__global__ __launch_bounds__(256, 2)
void quadform_kernel(const float* __restrict__ param,
                     const float* __restrict__ coef,
                     float* __restrict__ out) {
    // np.triu_indices(8) pair order
    static const int II[C_] = {0,0,0,0,0,0,0,0, 1,1,1,1,1,1,1, 2,2,2,2,2,2,
                               3,3,3,3,3, 4,4,4,4, 5,5,5, 6,6, 7};
    static const int JJ[C_] = {0,1,2,3,4,5,6,7, 1,2,3,4,5,6,7, 2,3,4,5,6,7,
                               3,4,5,6,7, 4,5,6,7, 5,6,7, 6,7, 7};

    const int tid  = threadIdx.x;
    const int lane = tid & 63;
    const int wv   = tid >> 6;                       // 4 waves/block
    const int b0   = blockIdx.x * R_;

    __shared__ float red[4][R_];

    float s[R_] = {0.0f, 0.0f};

    const float4* pb = reinterpret_cast<const float4*>(param);
    const float4* cb = reinterpret_cast<const float4*>(coef);
    const size_t bstep = (size_t)GG_ * 2;            // float4 units per b

    for (int pass = 0; pass < 4; ++pass) {           // 4*256 = 1024 >= 961
        const int  gh    = pass * 256 + tid;
        const bool valid = gh < GG_;
        const int  ghc   = valid ? gh : (GG_ - 1);   // clamp for safe addressing

        // ---- param: 4 x dwordx4, issued up front (HBM latency) ----
        const size_t base = ((size_t)b0 * GG_ + ghc) * 2;
        float pv[R_][P_];
        #pragma unroll
        for (int r = 0; r < R_; ++r) {
            float4 a = pb[base + (size_t)r * bstep];
            float4 b = pb[base + (size_t)r * bstep + 1];
            pv[r][0] = a.x; pv[r][1] = a.y; pv[r][2] = a.z; pv[r][3] = a.w;
            pv[r][4] = b.x; pv[r][5] = b.y; pv[r][6] = b.z; pv[r][7] = b.w;
        }

        // ---- coeffs: stream 9 float4s (L2-resident, 144B/cell) ----
        const float4* cp = cb + (size_t)ghc * (C_ / 4);
        float acc[R_] = {0.0f, 0.0f};
        #pragma unroll
        for (int q = 0; q < C_ / 4; ++q) {
            const float4 c4 = cp[q];
            const float c4a[4] = {c4.x, c4.y, c4.z, c4.w};
            #pragma unroll
            for (int k = 0; k < 4; ++k) {
                const int c = 4 * q + k;
                const int i = II[c], j = JJ[c];
                #pragma unroll
                for (int r = 0; r < R_; ++r)
                    acc[r] = fmaf(c4a[k] * pv[r][i], pv[r][j], acc[r]);
            }
        }

        if (valid) {
            #pragma unroll
            for (int r = 0; r < R_; ++r) s[r] += acc[r];
        }
    }

    // ---- reduce: butterfly over 64 lanes (2 interleaved chains) ----
    #pragma unroll
    for (int off = 32; off; off >>= 1) {
        #pragma unroll
        for (int r = 0; r < R_; ++r) s[r] += __shfl_xor(s[r], off, 64);
    }
    if (lane == 0) {
        #pragma unroll
        for (int r = 0; r < R_; ++r) red[wv][r] = s[r];
    }
    __syncthreads();

    // ---- cross-wave: 4 partials per b, exclusive store ----
    if (tid < R_) {
        out[b0 + tid] = red[0][tid] + red[1][tid] + red[2][tid] + red[3][tid];
    }
}

extern "C" void kernel_launch(void* const* d_in, const int* in_sizes, int n_in,
                              void* d_out, int out_size, void* d_ws, size_t ws_size,
                              hipStream_t stream) {
    const float* param = (const float*)d_in[0];   // [B, G, G, P] fp32
    const float* coef  = (const float*)d_in[1];   // [G, G, C]  fp32
    float* out = (float*)d_out;                   // [B] fp32

    quadform_kernel<<<B_ / R_, 256, 0, stream>>>(param, coef, out);  // 2048 blocks
}

// Round 6
// 185.873 us; speedup vs baseline: 1.0037x; 1.0037x over previous
//
#include <hip/hip_runtime.h>

#define B_  4096
#define G_  31
#define GG_ 961      // G*G
#define P_  8
#define C_  36       // P*(P+1)/2
#define NQ_ 9        // C/4 coeff quads
#define R_  2        // b-values per block (register-pressure-first)

// Pass 0: transpose coef [gh][9 quads] -> quad-major ct [q][gh] (float4 units)
// so the main kernel's per-lane coeff loads are lane-contiguous (coalesced
// 1024B/inst) instead of 144B-stride divergent gathers (64 cache lines/inst,
// ~64 serialized tag lookups in the per-CU TA — the round-1..5 shared floor).
__global__ void transpose_coef(const float4* __restrict__ in,
                               float4* __restrict__ ct) {
    int t = blockIdx.x * blockDim.x + threadIdx.x;   // 0 .. 9*961
    if (t < NQ_ * GG_) {
        int q  = t / GG_;
        int gh = t - q * GG_;
        ct[t] = in[gh * NQ_ + q];                    // coalesced writes
    }
}

// Main: block = 256 threads = 4 waves, owns R_=2 consecutive b's, sweeps all
// 961 gh cells in 4 passes of 256. Param read once, coalesced (64 lanes x 32B
// contiguous per wave per b). Coeffs from transposed ct: 9 coalesced dwordx4
// per pass, L2-resident. Live state (pv 16 + 9 hoisted quads 36 + acc/s 4 +
// addr ~8) ~= 64 -> spill-proof at any occupancy the allocator picks (R3
// showed it squeezes to 64 VGPR and spills wholesale past that).
// Reduction: 64-lane butterfly -> LDS -> exclusive store (no atomics).
__global__ __launch_bounds__(256, 2)
void quadform_kernel(const float* __restrict__ param,
                     const float4* __restrict__ ct,
                     float* __restrict__ out) {
    // np.triu_indices(8) pair order
    static const int II[C_] = {0,0,0,0,0,0,0,0, 1,1,1,1,1,1,1, 2,2,2,2,2,2,
                               3,3,3,3,3, 4,4,4,4, 5,5,5, 6,6, 7};
    static const int JJ[C_] = {0,1,2,3,4,5,6,7, 1,2,3,4,5,6,7, 2,3,4,5,6,7,
                               3,4,5,6,7, 4,5,6,7, 5,6,7, 6,7, 7};

    const int tid  = threadIdx.x;
    const int lane = tid & 63;
    const int wv   = tid >> 6;                       // 4 waves/block
    const int b0   = blockIdx.x * R_;

    __shared__ float red[4][R_];

    float s[R_] = {0.0f, 0.0f};

    const float4* pb = reinterpret_cast<const float4*>(param);
    const size_t bstep = (size_t)GG_ * 2;            // float4 units per b

    for (int pass = 0; pass < 4; ++pass) {           // 4*256 = 1024 >= 961
        const int  gh    = pass * 256 + tid;
        const bool valid = gh < GG_;
        const int  ghc   = valid ? gh : (GG_ - 1);   // clamp for safe addressing

        // ---- param: 4 x dwordx4, issued up front (HBM latency) ----
        const size_t base = ((size_t)b0 * GG_ + ghc) * 2;
        float pv[R_][P_];
        #pragma unroll
        for (int r = 0; r < R_; ++r) {
            float4 a = pb[base + (size_t)r * bstep];
            float4 b = pb[base + (size_t)r * bstep + 1];
            pv[r][0] = a.x; pv[r][1] = a.y; pv[r][2] = a.z; pv[r][3] = a.w;
            pv[r][4] = b.x; pv[r][5] = b.y; pv[r][6] = b.z; pv[r][7] = b.w;
        }

        // ---- coeffs: 9 coalesced dwordx4 from quad-major layout ----
        float acc[R_] = {0.0f, 0.0f};
        #pragma unroll
        for (int q = 0; q < NQ_; ++q) {
            const float4 c4 = ct[(size_t)q * GG_ + ghc];
            const float c4a[4] = {c4.x, c4.y, c4.z, c4.w};
            #pragma unroll
            for (int k = 0; k < 4; ++k) {
                const int c = 4 * q + k;
                const int i = II[c], j = JJ[c];
                #pragma unroll
                for (int r = 0; r < R_; ++r)
                    acc[r] = fmaf(c4a[k] * pv[r][i], pv[r][j], acc[r]);
            }
        }

        if (valid) {
            #pragma unroll
            for (int r = 0; r < R_; ++r) s[r] += acc[r];
        }
    }

    // ---- reduce: butterfly over 64 lanes (2 interleaved chains) ----
    #pragma unroll
    for (int off = 32; off; off >>= 1) {
        #pragma unroll
        for (int r = 0; r < R_; ++r) s[r] += __shfl_xor(s[r], off, 64);
    }
    if (lane == 0) {
        #pragma unroll
        for (int r = 0; r < R_; ++r) red[wv][r] = s[r];
    }
    __syncthreads();

    // ---- cross-wave: 4 partials per b, exclusive store ----
    if (tid < R_) {
        out[b0 + tid] = red[0][tid] + red[1][tid] + red[2][tid] + red[3][tid];
    }
}

extern "C" void kernel_launch(void* const* d_in, const int* in_sizes, int n_in,
                              void* d_out, int out_size, void* d_ws, size_t ws_size,
                              hipStream_t stream) {
    const float*  param = (const float*)d_in[0];   // [B, G, G, P] fp32
    const float4* coefq = (const float4*)d_in[1];  // [G, G, C] fp32 as 9 quads/cell
    float4* ct  = (float4*)d_ws;                   // [9][GG] float4 (138 KB)
    float*  out = (float*)d_out;                   // [B] fp32

    transpose_coef<<<(NQ_ * GG_ + 255) / 256, 256, 0, stream>>>(coefq, ct);
    quadform_kernel<<<B_ / R_, 256, 0, stream>>>(param, ct, out);  // 2048 blocks
}